// Round 1
// baseline (274.266 us; speedup 1.0000x reference)
//
#include <hip/hip_runtime.h>
#include <hip/hip_bf16.h>
#include <hip/hip_fp16.h>

// Problem constants: B=2, N=10000, M=320000, QD=KD=HD=256, NUM_HEADS=8, dh=32.
#define DHID 256
#define NHEAD 8
#define BATCH 2

typedef _Float16 h8 __attribute__((ext_vector_type(8)));
typedef _Float16 h2 __attribute__((ext_vector_type(2)));
typedef float f4 __attribute__((ext_vector_type(4)));

// ---------------- P0: W transpose->fp16 (z<2) + edge src histogram (z==2) --
// hist rides on prep so it costs no extra launch; cnt is memset on stream
// before this kernel.
__global__ __launch_bounds__(256) void prep_kernel(
    const float* __restrict__ Wq, const float* __restrict__ Wk,
    _Float16* __restrict__ Wtq, _Float16* __restrict__ Wtk,
    const int* __restrict__ mask, int* __restrict__ cnt, int M)
{
    if (blockIdx.z == 2) {          // histogram of mask[0] (src) over N bins
        const int tid = threadIdx.y * 32 + threadIdx.x;
        const int bid = blockIdx.y * 8 + blockIdx.x;     // 64 blocks
        for (int e = bid * 256 + tid; e < M; e += 64 * 256)
            atomicAdd(&cnt[mask[e]], 1);
        return;
    }
    const float* W = blockIdx.z ? Wk : Wq;
    _Float16* Wt   = blockIdx.z ? Wtk : Wtq;
    __shared__ float tile[32][33];
    const int tx = threadIdx.x;   // 0..31
    const int ty = threadIdx.y;   // 0..7
    const int n0 = blockIdx.x * 32;
    const int k0 = blockIdx.y * 32;
#pragma unroll
    for (int j = 0; j < 32; j += 8)
        tile[ty + j][tx] = W[(size_t)(k0 + ty + j) * DHID + n0 + tx];
    __syncthreads();
#pragma unroll
    for (int j = 0; j < 32; j += 8)
        Wt[(size_t)(n0 + ty + j) * DHID + k0 + tx] = (_Float16)tile[tx][ty + j];
}

// ---------------- P1: exclusive prefix sum cnt -> cur (1 block) ------------
__global__ __launch_bounds__(1024) void scan_kernel(
    const int* __restrict__ cnt, int* __restrict__ cur, int N)
{
    __shared__ int sums[1024];
    const int t = threadIdx.x;
    const int per = (N + 1023) >> 10;
    const int base = t * per;
    int s = 0;
    for (int i = 0; i < per; ++i) {
        int j = base + i;
        if (j < N) s += cnt[j];
    }
    sums[t] = s;
    __syncthreads();
    for (int off = 1; off < 1024; off <<= 1) {      // Hillis-Steele inclusive
        int v = (t >= off) ? sums[t - off] : 0;
        __syncthreads();
        sums[t] += v;
        __syncthreads();
    }
    int run = (t == 0) ? 0 : sums[t - 1];
    for (int i = 0; i < per; ++i) {
        int j = base + i;
        if (j < N) { cur[j] = run; run += cnt[j]; }
    }
}

// ---------------- MFMA GEMM, A-stationary (626-block r11 winner) ----------
// Spare blocks (x >= nx): z==0 zeros seg, z==1 scatters edges into
// src-sorted order (ssrc/sdst/seid) using the cur cursors — both side jobs
// hide entirely under the GEMM (gemm never reads seg or the sort arrays).
__global__ __launch_bounds__(256, 2) void gemm_mfma(
    const float* __restrict__ Xq, const float* __restrict__ Xk,
    const _Float16* __restrict__ Wtq, const _Float16* __restrict__ Wtk,
    _Float16* __restrict__ Qh, _Float16* __restrict__ Kh,
    float* __restrict__ seg, int segN, int nx, int Mrows,
    const int* __restrict__ mask, int* __restrict__ cur,
    int* __restrict__ ssrc, int* __restrict__ sdst, int* __restrict__ seid,
    int M)
{
    const int t = threadIdx.x;
    if ((int)blockIdx.x >= nx) {
        const int sb = (int)blockIdx.x - nx;         // 0..63
        if (blockIdx.z == 0) {                       // seg-zero side job
            f4 z = {0.f, 0.f, 0.f, 0.f};
            for (int i = sb * 256 + t; i < segN / 4; i += 64 * 256)
                ((f4*)seg)[i] = z;
        } else {                                     // counting-sort scatter
            for (int e = sb * 256 + t; e < M; e += 64 * 256) {
                int s = mask[e];
                int d = mask[M + e];
                int pos = atomicAdd(&cur[s], 1);
                ssrc[pos] = s; sdst[pos] = d; seid[pos] = e;
            }
        }
        return;
    }

    const float* X       = blockIdx.z ? Xk : Xq;
    const _Float16* Wt   = blockIdx.z ? Wtk : Wtq;
    _Float16* C          = blockIdx.z ? Kh : Qh;

    __shared__ _Float16 As[64 * 256];   // 32 KB, [row][k] swizzled
    __shared__ _Float16 Bs[64 * 256];   // 32 KB, [n][k]   swizzled

    const int lane = t & 63;
    const int wave = t >> 6;
    const int rowBase = blockIdx.x * 64;

#pragma unroll
    for (int i = 0; i < 8; ++i) {
        int idx = t + i * 256;          // 0..2047
        int row = idx >> 5;
        int c   = idx & 31;
        int grow = rowBase + row;
        f4 v0 = {0,0,0,0}, v1 = {0,0,0,0};
        if (grow < Mrows) {
            const float* p = X + (size_t)grow * DHID + c * 8;
            v0 = *(const f4*)p;
            v1 = *(const f4*)(p + 4);
        }
        h8 hv;
        hv[0]=(_Float16)v0[0]; hv[1]=(_Float16)v0[1]; hv[2]=(_Float16)v0[2]; hv[3]=(_Float16)v0[3];
        hv[4]=(_Float16)v1[0]; hv[5]=(_Float16)v1[1]; hv[6]=(_Float16)v1[2]; hv[7]=(_Float16)v1[3];
        int sc = c ^ (row & 7);
        *(h8*)&As[row * 256 + sc * 8] = hv;
    }

    const int ar   = wave * 16 + (lane & 15);
    const int quad = lane >> 4;

    for (int ct64 = 0; ct64 < 4; ++ct64) {
#pragma unroll
        for (int i = 0; i < 8; ++i) {
            int idx = t + i * 256;
            int n = idx >> 5;
            int c = idx & 31;
            h8 hv = *(const h8*)(Wt + (size_t)(ct64 * 64 + n) * DHID + c * 8);
            int sc = c ^ (n & 7);
            *(h8*)&Bs[n * 256 + sc * 8] = hv;
        }
        __syncthreads();

        f4 acc[4] = {{0,0,0,0},{0,0,0,0},{0,0,0,0},{0,0,0,0}};
#pragma unroll
        for (int kc = 0; kc < 8; ++kc) {            // K chunk of 32
            int ac = (kc * 4 + quad) ^ (ar & 7);
            h8 afrag = *(const h8*)&As[ar * 256 + ac * 8];
#pragma unroll
            for (int ct = 0; ct < 4; ++ct) {
                int bn = ct * 16 + (lane & 15);
                int bc = (kc * 4 + quad) ^ (bn & 7);
                h8 bfrag = *(const h8*)&Bs[bn * 256 + bc * 8];
                acc[ct] = __builtin_amdgcn_mfma_f32_16x16x32_f16(afrag, bfrag, acc[ct], 0, 0, 0);
            }
        }

#pragma unroll
        for (int ct = 0; ct < 4; ++ct) {
#pragma unroll
            for (int r = 0; r < 4; ++r) {
                int grow = rowBase + wave * 16 + quad * 4 + r;
                if (grow < Mrows)
                    C[(size_t)grow * DHID + ct64 * 64 + ct * 16 + (lane & 15)] = (_Float16)acc[ct][r];
            }
        }
        __syncthreads();
    }
}

// ---------------- Edge kernel, src-sorted order ----------------------------
// Processes edges in counting-sorted (by src) order: consecutive 8-edge wave
// groups share a Q row (avg degree 32) -> Q gathers hit L1/L2, halving the
// per-CU L2-miss load that capped the unsorted version at ~64us.
// K[dst] stays random (the remaining miss traffic). eh is written at the
// ORIGINAL edge id (seid) so norm_kernel stays coalesced and unchanged.
// Dot product via v_dot2_f32_f16 (4 ops vs ~24 cvt/fma).
__global__ __launch_bounds__(256, 8) void edge_kernel(
    const _Float16* __restrict__ Qh, const _Float16* __restrict__ Kh,
    const int* __restrict__ ssrc, const int* __restrict__ sdst,
    const int* __restrict__ seid, _Float16* __restrict__ eh,
    float* __restrict__ seg, int M, int N)
{
    const int lane = threadIdx.x & 63;
    const int wave = threadIdx.x >> 6;
    const int c    = lane & 31;     // 16B chunk within row (c*8 halves)
    const int half = lane >> 5;     // which edge of the pair
    const int h    = c >> 2;        // head of this chunk
    const long e0 = ((long)blockIdx.x * 4 + wave) * 8;
    const int b = blockIdx.y;
    if (e0 >= M) return;

    // lanes 0..7: sorted src; 8..15: sorted dst; 16..23: original edge id
    int idxv = 0;
    {
        long le = e0 + (lane & 7);
        if (le >= M) le = M - 1;
        if (lane < 8)       idxv = ssrc[le];
        else if (lane < 16) idxv = sdst[le];
        else if (lane < 24) idxv = seid[le];
    }

    const _Float16* Qb = Qh + (size_t)b * N * DHID;
    const _Float16* Kb = Kh + (size_t)b * N * DHID;

    int sidx[4], didx[4], eidx[4];
#pragma unroll
    for (int p = 0; p < 4; ++p) {
        sidx[p] = __shfl(idxv, p * 2 + half);
        didx[p] = __shfl(idxv, 8 + p * 2 + half);
        eidx[p] = __shfl(idxv, 16 + p * 2 + half);
    }

    // ---- load phase: K (likely misses) first to fill the miss queue,
    //      then Q (likely L1 hits after the sort) ----
    h8 qv[4], kv[4];
#pragma unroll
    for (int p = 0; p < 4; ++p)
        kv[p] = *(const h8*)(Kb + (size_t)didx[p] * DHID + c * 8);
#pragma unroll
    for (int p = 0; p < 4; ++p)
        qv[p] = *(const h8*)(Qb + (size_t)sidx[p] * DHID + c * 8);

    // ---- compute + emit ----
#pragma unroll
    for (int p = 0; p < 4; ++p) {
        float s = 0.f;
#if __has_builtin(__builtin_amdgcn_fdot2)
#pragma unroll
        for (int u = 0; u < 4; ++u) {
            h2 a, bb;
            a[0]  = qv[p][2 * u]; a[1]  = qv[p][2 * u + 1];
            bb[0] = kv[p][2 * u]; bb[1] = kv[p][2 * u + 1];
            s = __builtin_amdgcn_fdot2(a, bb, s, false);
        }
#else
#pragma unroll
        for (int u = 0; u < 8; ++u)
            s += (float)qv[p][u] * (float)kv[p][u];
#endif
        s += __shfl_xor(s, 1);
        s += __shfl_xor(s, 2);          // quad c&~3..c|3 now holds head sum
        const long e = e0 + p * 2 + half;
        if ((c & 3) == 0 && e < M) {
            _Float16 evh = (_Float16)expf(s * 0.0625f);   // 1/sqrt(256)
            // scattered (original-order) store; plain store so L2 can merge
            eh[((size_t)b * M + eidx[p]) * NHEAD + h] = evh;
            atomicAdd(seg + ((size_t)b * N + sidx[p]) * NHEAD + h, (float)evh);
        }
    }
}

// ---------------- Normalize: out = eh / (seg[src] + 1e-16) ----------------
__global__ __launch_bounds__(256) void norm_kernel(
    const int* __restrict__ mask, const float* __restrict__ seg,
    const _Float16* __restrict__ eh, float* __restrict__ out,
    int M, int N, int BM)
{
    int idx = blockIdx.x * 256 + threadIdx.x;   // idx = b*M + e
    if (idx >= BM) return;
    int b = idx / M;
    int e = idx - b * M;
    int src = mask[e];
    const f4* s4 = (const f4*)(seg + ((size_t)b * N + src) * NHEAD);
    f4 s0 = s4[0], s1 = s4[1];
    h8 ev = *(const h8*)(eh + (size_t)idx * NHEAD);
    f4 o0, o1;
    o0[0] = (float)ev[0] * __builtin_amdgcn_rcpf(s0[0] + 1e-16f);
    o0[1] = (float)ev[1] * __builtin_amdgcn_rcpf(s0[1] + 1e-16f);
    o0[2] = (float)ev[2] * __builtin_amdgcn_rcpf(s0[2] + 1e-16f);
    o0[3] = (float)ev[3] * __builtin_amdgcn_rcpf(s0[3] + 1e-16f);
    o1[0] = (float)ev[4] * __builtin_amdgcn_rcpf(s1[0] + 1e-16f);
    o1[1] = (float)ev[5] * __builtin_amdgcn_rcpf(s1[1] + 1e-16f);
    o1[2] = (float)ev[6] * __builtin_amdgcn_rcpf(s1[2] + 1e-16f);
    o1[3] = (float)ev[7] * __builtin_amdgcn_rcpf(s1[3] + 1e-16f);
    f4* o4 = (f4*)(out + (size_t)idx * NHEAD);
    __builtin_nontemporal_store(o0, &o4[0]);
    __builtin_nontemporal_store(o1, &o4[1]);
}

extern "C" void kernel_launch(void* const* d_in, const int* in_sizes, int n_in,
                              void* d_out, int out_size, void* d_ws, size_t ws_size,
                              hipStream_t stream) {
    const float* x_q  = (const float*)d_in[0];
    const float* x_k  = (const float*)d_in[1];
    const int*   mask = (const int*)d_in[2];
    const float* w_q  = (const float*)d_in[3];
    const float* w_k  = (const float*)d_in[4];
    float* out = (float*)d_out;

    const int M = in_sizes[2] / 2;                 // 320000
    const int N = in_sizes[0] / (BATCH * DHID);    // 10000
    const int Mrows = BATCH * N;                   // 20000
    const int segN  = BATCH * N * NHEAD;

    _Float16* Qh  = (_Float16*)d_ws;
    _Float16* Kh  = Qh  + (size_t)Mrows * DHID;
    _Float16* Wtq = Kh  + (size_t)Mrows * DHID;
    _Float16* Wtk = Wtq + (size_t)DHID * DHID;
    float*    seg = (float*)(Wtk + (size_t)DHID * DHID);
    _Float16* eh  = (_Float16*)(seg + (size_t)segN);
    int*      cnt = (int*)(eh + (size_t)BATCH * M * NHEAD);
    int*      cur = cnt + N;
    int*      ssrc = cur + N;
    int*      sdst = ssrc + M;
    int*      seid = sdst + M;

    // zero the histogram bins (capturable memset node)
    hipMemsetAsync(cnt, 0, (size_t)N * sizeof(int), stream);

    // P0: transpose W to fp16 (z<2) + src histogram (z==2)
    prep_kernel<<<dim3(DHID / 32, DHID / 32, 3), dim3(32, 8), 0, stream>>>(
        w_q, w_k, Wtq, Wtk, mask, cnt, M);

    // P1: exclusive scan -> group cursors
    scan_kernel<<<1, 1024, 0, stream>>>(cnt, cur, N);

    // GEMM: 626 blocks + 64 seg-zero blocks (z=0) + 64 scatter blocks (z=1)
    const int nx = (Mrows + 63) / 64;              // 313
    gemm_mfma<<<dim3(nx + 64, 1, 2), 256, 0, stream>>>(
        x_q, x_k, Wtq, Wtk, Qh, Kh, seg, segN, nx, Mrows,
        mask, cur, ssrc, sdst, seid, M);

    // edge: 8 sorted edges per wave, 4 waves per block
    long waves = (M + 7) / 8;
    dim3 egrid((unsigned)((waves + 3) / 4), BATCH);
    edge_kernel<<<egrid, 256, 0, stream>>>(Qh, Kh, ssrc, sdst, seid, eh, seg, M, N);

    const int BM = BATCH * M;
    norm_kernel<<<(BM + 255) / 256, 256, 0, stream>>>(mask, seg, eh, out, M, N, BM);
}

// Round 2
// 217.726 us; speedup vs baseline: 1.2597x; 1.2597x over previous
//
#include <hip/hip_runtime.h>
#include <hip/hip_bf16.h>
#include <hip/hip_fp16.h>

// Problem constants: B=2, N=10000, M=320000, QD=KD=HD=256, NUM_HEADS=8, dh=32.
#define DHID 256
#define NHEAD 8
#define BATCH 2

typedef _Float16 h8 __attribute__((ext_vector_type(8)));
typedef _Float16 h2 __attribute__((ext_vector_type(2)));
typedef float f4 __attribute__((ext_vector_type(4)));

// ---------------- hist: cnt[src]++ over all edges (cnt pre-zeroed) ---------
__global__ __launch_bounds__(256) void hist_kernel(
    const int* __restrict__ mask, int* __restrict__ cnt, int M)
{
    int e = blockIdx.x * 256 + threadIdx.x;
    if (e < M) atomicAdd(&cnt[mask[e]], 1);   // no return value -> fire&forget
}

// ---------------- scan: exclusive prefix sum cnt -> cur (1 block) ----------
__global__ __launch_bounds__(1024) void scan_kernel(
    const int* __restrict__ cnt, int* __restrict__ cur, int N)
{
    __shared__ int sums[1024];
    const int t = threadIdx.x;
    const int per = (N + 1023) >> 10;
    const int base = t * per;
    int s = 0;
    for (int i = 0; i < per; ++i) {
        int j = base + i;
        if (j < N) s += cnt[j];
    }
    sums[t] = s;
    __syncthreads();
    for (int off = 1; off < 1024; off <<= 1) {      // Hillis-Steele inclusive
        int v = (t >= off) ? sums[t - off] : 0;
        __syncthreads();
        sums[t] += v;
        __syncthreads();
    }
    int run = (t == 0) ? 0 : sums[t - 1];
    for (int i = 0; i < per; ++i) {
        int j = base + i;
        if (j < N) { cur[j] = run; run += cnt[j]; }
    }
}

// ---------------- scatter: counting-sort edges by src ----------------------
// 1 edge/thread: independent atomics, no dependent chains. After this,
// cur[src] holds the END offset of src's group (start = end - cnt[src]).
__global__ __launch_bounds__(256) void scatter_kernel(
    const int* __restrict__ mask, int* __restrict__ cur,
    int* __restrict__ sdst, int* __restrict__ seid, int M)
{
    int e = blockIdx.x * 256 + threadIdx.x;
    if (e >= M) return;
    int s = mask[e];
    int pos = atomicAdd(&cur[s], 1);
    sdst[pos] = mask[M + e];
    seid[pos] = e;
}

// ---------------- P0: W transpose -> fp16 ---------------------------------
__global__ __launch_bounds__(256) void prep_kernel(
    const float* __restrict__ Wq, const float* __restrict__ Wk,
    _Float16* __restrict__ Wtq, _Float16* __restrict__ Wtk)
{
    const float* W = blockIdx.z ? Wk : Wq;
    _Float16* Wt   = blockIdx.z ? Wtk : Wtq;
    __shared__ float tile[32][33];
    const int tx = threadIdx.x;   // 0..31
    const int ty = threadIdx.y;   // 0..7
    const int n0 = blockIdx.x * 32;
    const int k0 = blockIdx.y * 32;
#pragma unroll
    for (int j = 0; j < 32; j += 8)
        tile[ty + j][tx] = W[(size_t)(k0 + ty + j) * DHID + n0 + tx];
    __syncthreads();
#pragma unroll
    for (int j = 0; j < 32; j += 8)
        Wt[(size_t)(n0 + ty + j) * DHID + k0 + tx] = (_Float16)tile[tx][ty + j];
}

// ---------------- MFMA GEMM, A-stationary (pure r0 form, no side jobs) ----
__global__ __launch_bounds__(256, 2) void gemm_mfma(
    const float* __restrict__ Xq, const float* __restrict__ Xk,
    const _Float16* __restrict__ Wtq, const _Float16* __restrict__ Wtk,
    _Float16* __restrict__ Qh, _Float16* __restrict__ Kh, int Mrows)
{
    const int t = threadIdx.x;
    const float* X       = blockIdx.z ? Xk : Xq;
    const _Float16* Wt   = blockIdx.z ? Wtk : Wtq;
    _Float16* C          = blockIdx.z ? Kh : Qh;

    __shared__ _Float16 As[64 * 256];   // 32 KB, [row][k] swizzled
    __shared__ _Float16 Bs[64 * 256];   // 32 KB, [n][k]   swizzled

    const int lane = t & 63;
    const int wave = t >> 6;
    const int rowBase = blockIdx.x * 64;

#pragma unroll
    for (int i = 0; i < 8; ++i) {
        int idx = t + i * 256;          // 0..2047
        int row = idx >> 5;
        int c   = idx & 31;
        int grow = rowBase + row;
        f4 v0 = {0,0,0,0}, v1 = {0,0,0,0};
        if (grow < Mrows) {
            const float* p = X + (size_t)grow * DHID + c * 8;
            v0 = *(const f4*)p;
            v1 = *(const f4*)(p + 4);
        }
        h8 hv;
        hv[0]=(_Float16)v0[0]; hv[1]=(_Float16)v0[1]; hv[2]=(_Float16)v0[2]; hv[3]=(_Float16)v0[3];
        hv[4]=(_Float16)v1[0]; hv[5]=(_Float16)v1[1]; hv[6]=(_Float16)v1[2]; hv[7]=(_Float16)v1[3];
        int sc = c ^ (row & 7);
        *(h8*)&As[row * 256 + sc * 8] = hv;
    }

    const int ar   = wave * 16 + (lane & 15);
    const int quad = lane >> 4;

    for (int ct64 = 0; ct64 < 4; ++ct64) {
#pragma unroll
        for (int i = 0; i < 8; ++i) {
            int idx = t + i * 256;
            int n = idx >> 5;
            int c = idx & 31;
            h8 hv = *(const h8*)(Wt + (size_t)(ct64 * 64 + n) * DHID + c * 8);
            int sc = c ^ (n & 7);
            *(h8*)&Bs[n * 256 + sc * 8] = hv;
        }
        __syncthreads();

        f4 acc[4] = {{0,0,0,0},{0,0,0,0},{0,0,0,0},{0,0,0,0}};
#pragma unroll
        for (int kc = 0; kc < 8; ++kc) {            // K chunk of 32
            int ac = (kc * 4 + quad) ^ (ar & 7);
            h8 afrag = *(const h8*)&As[ar * 256 + ac * 8];
#pragma unroll
            for (int ct = 0; ct < 4; ++ct) {
                int bn = ct * 16 + (lane & 15);
                int bc = (kc * 4 + quad) ^ (bn & 7);
                h8 bfrag = *(const h8*)&Bs[bn * 256 + bc * 8];
                acc[ct] = __builtin_amdgcn_mfma_f32_16x16x32_f16(afrag, bfrag, acc[ct], 0, 0, 0);
            }
        }

#pragma unroll
        for (int ct = 0; ct < 4; ++ct) {
#pragma unroll
            for (int r = 0; r < 4; ++r) {
                int grow = rowBase + wave * 16 + quad * 4 + r;
                if (grow < Mrows)
                    C[(size_t)grow * DHID + ct64 * 64 + ct * 16 + (lane & 15)] = (_Float16)acc[ct][r];
            }
        }
        __syncthreads();
    }
}

// ---------------- Edge kernel: one wave per (batch, src) group -------------
// Q row loaded ONCE per group into registers (captures the deg~32 reuse that
// round-1's sort exposed: FETCH 204->92MB). Per-head group sums accumulate
// in registers -> no seg array, no atomics, no contention. ev written fp16
// to a sorted-order buffer (L2-hot), re-read by the SAME lanes (same-thread
// visibility, no fence needed), normalized, and scattered to out at the
// original edge id -> norm_kernel eliminated.
__global__ __launch_bounds__(256, 8) void edge_kernel(
    const _Float16* __restrict__ Qh, const _Float16* __restrict__ Kh,
    const int* __restrict__ cnt, const int* __restrict__ cur,
    const int* __restrict__ sdst, const int* __restrict__ seid,
    _Float16* __restrict__ ehs, float* __restrict__ out, int M, int N)
{
    const int lane = threadIdx.x & 63;
    const int wave = threadIdx.x >> 6;
    const int c    = lane & 31;     // 16B chunk within row (c*8 halves)
    const int half = lane >> 5;     // which edge of the pair
    const int h    = c >> 2;        // head of this chunk
    const int src  = blockIdx.x * 4 + wave;
    const int b    = blockIdx.y;
    if (src >= N) return;
    const int deg = cnt[src];
    if (deg == 0) return;
    const int end   = cur[src];         // post-scatter cursor = group end
    const int start = end - deg;

    const _Float16* Qb = Qh + (size_t)b * N * DHID;
    const _Float16* Kb = Kh + (size_t)b * N * DHID;

    // Q row: resident in registers for the whole group (both halves share it)
    const h8 qv = *(const h8*)(Qb + (size_t)src * DHID + c * 8);

    // ---- pass 1: dot, exp, sorted-order ev store, register seg-sum ----
    float segacc = 0.f;                 // valid on lanes with (c&3)==0
    for (int it = start; it < end; it += 8) {
        int dv = 0;
        {
            int le = it + lane;         // lanes 0..7 feed the shfl
            if (le >= end) le = end - 1;
            if (lane < 8) dv = sdst[le];
        }
        int pos[4]; h8 kv[4];
#pragma unroll
        for (int p = 0; p < 4; ++p) {
            pos[p] = it + p * 2 + half;
            int d = __shfl(dv, p * 2 + half);
            kv[p] = *(const h8*)(Kb + (size_t)d * DHID + c * 8);
        }
#pragma unroll
        for (int p = 0; p < 4; ++p) {
            float s = 0.f;
#if __has_builtin(__builtin_amdgcn_fdot2)
#pragma unroll
            for (int u = 0; u < 4; ++u) {
                h2 a, bb;
                a[0]  = qv[2 * u];    a[1]  = qv[2 * u + 1];
                bb[0] = kv[p][2 * u]; bb[1] = kv[p][2 * u + 1];
                s = __builtin_amdgcn_fdot2(a, bb, s, false);
            }
#else
#pragma unroll
            for (int u = 0; u < 8; ++u)
                s += (float)qv[u] * (float)kv[p][u];
#endif
            s += __shfl_xor(s, 1);
            s += __shfl_xor(s, 2);      // quad c&~3..c|3 holds head sum
            if ((c & 3) == 0 && pos[p] < end) {
                _Float16 evh = (_Float16)expf(s * 0.0625f);   // 1/sqrt(256)
                ehs[((size_t)b * M + pos[p]) * NHEAD + h] = evh;  // sorted, L2-hot
                segacc += (float)evh;
            }
        }
    }

    // combine the two halves' partial sums; all active lanes get the total
    segacc += __shfl_xor(segacc, 32);
    const float rs = __builtin_amdgcn_rcpf(segacc + 1e-16f);

    // ---- pass 2: same-lane re-read of own ev, normalize, scatter to out ----
    for (int it = start; it < end; it += 8) {
        int iv = 0;
        {
            int le = it + lane;
            if (le >= end) le = end - 1;
            if (lane < 8) iv = seid[le];
        }
#pragma unroll
        for (int p = 0; p < 4; ++p) {
            int pos = it + p * 2 + half;
            int eid = __shfl(iv, p * 2 + half);
            if ((c & 3) == 0 && pos < end) {
                float evh = (float)ehs[((size_t)b * M + pos) * NHEAD + h];
                __builtin_nontemporal_store(evh * rs,
                    &out[((size_t)b * M + eid) * NHEAD + h]);
            }
        }
    }
}

extern "C" void kernel_launch(void* const* d_in, const int* in_sizes, int n_in,
                              void* d_out, int out_size, void* d_ws, size_t ws_size,
                              hipStream_t stream) {
    const float* x_q  = (const float*)d_in[0];
    const float* x_k  = (const float*)d_in[1];
    const int*   mask = (const int*)d_in[2];
    const float* w_q  = (const float*)d_in[3];
    const float* w_k  = (const float*)d_in[4];
    float* out = (float*)d_out;

    const int M = in_sizes[2] / 2;                 // 320000
    const int N = in_sizes[0] / (BATCH * DHID);    // 10000
    const int Mrows = BATCH * N;                   // 20000

    _Float16* Qh  = (_Float16*)d_ws;
    _Float16* Kh  = Qh  + (size_t)Mrows * DHID;
    _Float16* Wtq = Kh  + (size_t)Mrows * DHID;
    _Float16* Wtk = Wtq + (size_t)DHID * DHID;
    _Float16* ehs = Wtk + (size_t)DHID * DHID;     // [B][M][NHEAD] fp16, sorted order
    int*      cnt = (int*)(ehs + (size_t)BATCH * M * NHEAD);
    int*      cur = cnt + N;
    int*      sdst = cur + N;
    int*      seid = sdst + M;

    // sort chain: cnt=0 -> hist -> scan -> scatter (all flat, no chains)
    hipMemsetAsync(cnt, 0, (size_t)N * sizeof(int), stream);
    hist_kernel<<<(M + 255) / 256, 256, 0, stream>>>(mask, cnt, M);
    scan_kernel<<<1, 1024, 0, stream>>>(cnt, cur, N);
    scatter_kernel<<<(M + 255) / 256, 256, 0, stream>>>(mask, cur, sdst, seid, M);

    // W transpose -> fp16
    prep_kernel<<<dim3(DHID / 32, DHID / 32, 2), dim3(32, 8), 0, stream>>>(
        w_q, w_k, Wtq, Wtk);

    // GEMM: pure 313 blocks x 2
    const int nx = (Mrows + 63) / 64;              // 313
    gemm_mfma<<<dim3(nx, 1, 2), 256, 0, stream>>>(
        x_q, x_k, Wtq, Wtk, Qh, Kh, Mrows);

    // edge: one wave per (b, src) group; fused normalize + scatter-out
    edge_kernel<<<dim3((N + 3) / 4, BATCH), 256, 0, stream>>>(
        Qh, Kh, cnt, cur, sdst, seid, ehs, out, M, N);
}